// Round 10
// baseline (2665.824 us; speedup 1.0000x reference)
//
#include <hip/hip_runtime.h>
#include <hip/hip_bf16.h>
#include <cstdint>
#include <cstddef>

// N=30000 nodes, E=480000 edges, HID=256, SW=512, NB=128 bundles of dim 2.
// Householder(2x2) collapses to planar rotation: x=X[1,0]; c=(x^2-1)/(1+x^2), s=2x/(1+x^2).
// enc feeds only enc_w1 => se_out GEMM eliminated via F_k = se_out_w @ enc_w1[k].

typedef __attribute__((ext_vector_type(8))) short short8;
typedef __attribute__((ext_vector_type(4))) float f32x4;

__device__ __forceinline__ float gelu_exact(float x) {
  return 0.5f * x * (1.0f + erff(x * 0.7071067811865475f));
}
__device__ __forceinline__ unsigned short f2bf(float f) {
  __hip_bfloat16 b = __float2bfloat16(f);
  return *reinterpret_cast<unsigned short*>(&b);
}
__device__ __forceinline__ float bf2f(unsigned short u) {
  return __uint_as_float((unsigned)u << 16);
}
__device__ __forceinline__ float bflo(unsigned u) { return __uint_as_float(u << 16); }
__device__ __forceinline__ float bfhi(unsigned u) { return __uint_as_float(u & 0xffff0000u); }
__device__ __forceinline__ unsigned packbf(float f0, float f1) {
  return (unsigned)f2bf(f0) | ((unsigned)f2bf(f1) << 16);
}
__device__ __forceinline__ void gload16(const void* g, void* l) {
  __builtin_amdgcn_global_load_lds((const __attribute__((address_space(1))) void*)g,
                                   (__attribute__((address_space(3))) void*)l, 16, 0, 0);
}
#define SCHEDB() __builtin_amdgcn_sched_barrier(0)

// ---------------- CSR build ----------------
__global__ void k_hist(const int* __restrict__ dst, int* __restrict__ deg, int E) {
  int i = blockIdx.x * 256 + threadIdx.x;
  if (i < E) atomicAdd(&deg[dst[i]], 1);
}

__global__ __launch_bounds__(1024)
void k_scan(const int* __restrict__ deg, int* __restrict__ rp, int* __restrict__ cur, int Nn) {
  __shared__ int part[1024];
  int t = threadIdx.x;
  int chunk = (Nn + 1023) >> 10;
  int s0 = t * chunk;
  int e0 = s0 + chunk; if (e0 > Nn) e0 = Nn;
  int s = 0;
  for (int i = s0; i < e0; ++i) s += deg[i];
  part[t] = s;
  __syncthreads();
  for (int off = 1; off < 1024; off <<= 1) {
    int v = (t >= off) ? part[t - off] : 0;
    __syncthreads();
    part[t] += v;
    __syncthreads();
  }
  int base = (t == 0) ? 0 : part[t - 1];
  for (int i = s0; i < e0; ++i) {
    rp[i] = base; cur[i] = base; base += deg[i];
  }
  if (t == 0) rp[Nn] = part[1023];
}

__global__ void k_fill(const int* __restrict__ src, const int* __restrict__ dst,
                       int* __restrict__ cur, int* __restrict__ srcs, int E) {
  int i = blockIdx.x * 256 + threadIdx.x;
  if (i < E) {
    int p = atomicAdd(&cur[dst[i]], 1);
    srcs[p] = src[i];
  }
}

// ---------------- batched weight transpose fp32 [K,N] -> bf16 [N,K] ----------------
__global__ void k_wT(const float* __restrict__ W, unsigned short* __restrict__ Wt, int K, int Nc) {
  const float* Ws = W + (size_t)blockIdx.y * K * Nc;
  unsigned short* Wd = Wt + (size_t)blockIdx.y * K * Nc;
  int idx = blockIdx.x * 256 + threadIdx.x;
  if (idx >= K * Nc) return;
  int k = idx % K, n = idx / K;                       // k fastest -> coalesced writes
  Wd[(size_t)n * K + k] = f2bf(Ws[(size_t)k * Nc + n]);
}

__global__ void k_cast(const float* __restrict__ src, unsigned short* __restrict__ dst, int n) {
  int i = blockIdx.x * 256 + threadIdx.x;
  if (i < n) dst[i] = f2bf(src[i]);
}

// fused bias: bf[k][n] = sum_e b_so[e]*enc_w1[k][e][n] + b_e1[k][n]
__global__ void k_bfuse(const float* __restrict__ b_so, const float* __restrict__ W_e1,
                        const float* __restrict__ b_e1, float* __restrict__ bf) {
  int k = blockIdx.y;
  int n = blockIdx.x * 256 + threadIdx.x;
  if (n >= 512) return;
  const float* W = W_e1 + (size_t)k * 512 * 512;
  float s = b_e1[(size_t)k * 512 + n];
  for (int e = 0; e < 512; ++e) s += b_so[e] * W[(size_t)e * 512 + n];
  bf[(size_t)k * 512 + n] = s;
}

// ---------------- 128x128 bf16 MFMA GEMM (proven; used for Nc=256) ----------------
// Depth-2 counted-vmcnt double-buffer, XCD co-location. RES: 0 none, 1 fp32, 2 bf16.
template<int ACT, int RES, bool DUAL, bool W32, bool WBF>
__global__ __launch_bounds__(256)
void k_mfma(const unsigned short* __restrict__ A1, const unsigned short* __restrict__ A2,
            int K1, int K2,
            const unsigned short* __restrict__ Wt, const float* __restrict__ bias,
            const float* R32, const unsigned short* Rbf,
            float* C32, unsigned short* Cbf, int M, int Nc) {
  const int mb_cnt = (M + 127) >> 7;
  const int nb_cnt = Nc >> 7;
  int u = blockIdx.x;
  int xcd = u & 7;
  int rest = u >> 3;
  int nb = rest % nb_cnt;
  int mb = (rest / nb_cnt) * 8 + xcd;
  if (mb >= mb_cnt) return;
  const int m0 = mb << 7, n0 = nb << 7;

  __shared__ unsigned short As[2][128 * 64];
  __shared__ unsigned short Bs[2][128 * 64];
  const int tid = threadIdx.x;
  const int lane = tid & 63, wv = tid >> 6;
  const int wr = (wv >> 1) * 64, wc = (wv & 1) * 64;
  const int rA = lane & 15, kg = lane >> 4;
  const int Ktot = K1 + K2;
  const int nt = Ktot >> 6;

  f32x4 acc[4][4];
#pragma unroll
  for (int m = 0; m < 4; ++m)
#pragma unroll
    for (int n = 0; n < 4; ++n)
#pragma unroll
      for (int r = 0; r < 4; ++r) acc[m][n][r] = 0.f;

  auto stage = [&](int t, int b) {
    int k0 = t << 6;
    const unsigned short* Asrc; int kc, lda;
    if (!DUAL || k0 < K1) { Asrc = A1; kc = k0; lda = K1; }
    else                  { Asrc = A2; kc = k0 - K1; lda = K2; }
#pragma unroll
    for (int is = 0; is < 4; ++is) {
      int chunk = is * 256 + tid;
      int row = chunk >> 3, seg = chunk & 7;
      int ks = seg ^ (row & 7);
      int gm = m0 + row; gm = gm < M ? gm : M - 1;
      gload16(Asrc + (size_t)gm * lda + kc + ks * 8, (char*)As[b] + (size_t)chunk * 16);
      gload16(Wt + (size_t)(n0 + row) * Ktot + k0 + ks * 8, (char*)Bs[b] + (size_t)chunk * 16);
    }
  };

  stage(0, 0);
  if (nt > 1) stage(1, 1);

  for (int t = 0; t < nt; ++t) {
    const int b = t & 1;
    if (t + 1 < nt) asm volatile("s_waitcnt vmcnt(8)" ::: "memory");
    else            asm volatile("s_waitcnt vmcnt(0)" ::: "memory");
    SCHEDB();
    __builtin_amdgcn_s_barrier();
    SCHEDB();

#pragma unroll
    for (int kk = 0; kk < 2; ++kk) {
      short8 bq[4], af[4];
#pragma unroll
      for (int n = 0; n < 4; ++n) {
        int col = wc + n * 16 + rA;
        int ks = (kk * 4 + kg) ^ (col & 7);
        bq[n] = *reinterpret_cast<const short8*>((const char*)Bs[b] + col * 128 + ks * 16);
      }
#pragma unroll
      for (int m = 0; m < 4; ++m) {
        int row = wr + m * 16 + rA;
        int ks = (kk * 4 + kg) ^ (row & 7);
        af[m] = *reinterpret_cast<const short8*>((const char*)As[b] + row * 128 + ks * 16);
      }
      __builtin_amdgcn_s_setprio(1);
#pragma unroll
      for (int m = 0; m < 4; ++m)
#pragma unroll
        for (int n = 0; n < 4; ++n)
          acc[m][n] = __builtin_amdgcn_mfma_f32_16x16x32_bf16(af[m], bq[n], acc[m][n], 0, 0, 0);
      __builtin_amdgcn_s_setprio(0);
    }
    asm volatile("s_waitcnt lgkmcnt(0)" ::: "memory");
    SCHEDB();
    __builtin_amdgcn_s_barrier();
    SCHEDB();
    if (t + 2 < nt) stage(t + 2, b);
  }

#pragma unroll
  for (int m = 0; m < 4; ++m) {
    int gr0 = m0 + wr + m * 16 + kg * 4;
#pragma unroll
    for (int n = 0; n < 4; ++n) {
      int gc = n0 + wc + n * 16 + rA;
      float bv = bias[gc];
#pragma unroll
      for (int r = 0; r < 4; ++r) {
        int gr = gr0 + r;
        if (gr < M) {
          float v = acc[m][n][r] + bv;
          if (ACT == 1) v = gelu_exact(v);
          if (RES == 1) v += R32[(size_t)gr * Nc + gc];
          if (RES == 2) v += bf2f(Rbf[(size_t)gr * Nc + gc]);
          if (W32) C32[(size_t)gr * Nc + gc] = v;
          if (WBF) Cbf[(size_t)gr * Nc + gc] = f2bf(v);
        }
      }
    }
  }
}

// ---------------- 256x256 bf16 MFMA GEMM (8 waves, phase-ordered interior) ----------------
// Waves 2(M)x4(N), per-wave 128x64 output (8x4 fragments). BK=64, 128 KiB LDS dbuf,
// depth-2 counted vmcnt(8). Interior written in phase order (per kk: B frags -> per mh:
// A frags -> 16 MFMA) so compiler's counted-lgkm scheduler overlaps ds_read with MFMA.
// OP: also emit planar-rotation params from the nr output (cols 4b+2).
template<int ACT, int RES, bool DUAL, bool W32, bool WBF, bool OP>
__global__ __launch_bounds__(512)
void k_mfma256(const unsigned short* __restrict__ A1, const unsigned short* __restrict__ A2,
               int K1, int K2,
               const unsigned short* __restrict__ Wt, const float* __restrict__ bias,
               const float* R32, const unsigned short* Rbf,
               float* C32, unsigned short* Cbf, float* Op, int M, int Nc) {
  const int mb_cnt = (M + 255) >> 8;
  const int nb_cnt = Nc >> 8;
  int u = blockIdx.x;
  int xcd = u & 7;
  int rest = u >> 3;
  int nb = rest % nb_cnt;
  int mb = (rest / nb_cnt) * 8 + xcd;
  if (mb >= mb_cnt) return;
  const int m0 = mb << 8, n0 = nb << 8;

  __shared__ unsigned short As[2][256 * 64];   // 32 KB per buf
  __shared__ unsigned short Bs[2][256 * 64];
  const int tid = threadIdx.x;
  const int lane = tid & 63, wv = tid >> 6;
  const int wm = wv >> 2, wn = wv & 3;          // 2 x 4 wave grid
  const int rA = lane & 15, kg = lane >> 4;
  const int Ktot = K1 + K2;
  const int nt = Ktot >> 6;

  f32x4 acc[8][4];
#pragma unroll
  for (int f = 0; f < 8; ++f)
#pragma unroll
    for (int n = 0; n < 4; ++n)
#pragma unroll
      for (int r = 0; r < 4; ++r) acc[f][n][r] = 0.f;

  auto stage = [&](int t, int b) {
    int k0 = t << 6;
    const unsigned short* Asrc; int kc, lda;
    if (!DUAL || k0 < K1) { Asrc = A1; kc = k0; lda = K1; }
    else                  { Asrc = A2; kc = k0 - K1; lda = K2; }
#pragma unroll
    for (int is = 0; is < 4; ++is) {
      int chunk = is * 512 + tid;
      int row = chunk >> 3, seg = chunk & 7;
      int ks = seg ^ (row & 7);
      int gm = m0 + row; gm = gm < M ? gm : M - 1;
      gload16(Asrc + (size_t)gm * lda + kc + ks * 8, (char*)As[b] + (size_t)chunk * 16);
      gload16(Wt + (size_t)(n0 + row) * Ktot + k0 + ks * 8, (char*)Bs[b] + (size_t)chunk * 16);
    }
  };

  stage(0, 0);
  if (nt > 1) stage(1, 1);

  for (int t = 0; t < nt; ++t) {
    const int b = t & 1;
    if (t + 1 < nt) asm volatile("s_waitcnt vmcnt(8)" ::: "memory");
    else            asm volatile("s_waitcnt vmcnt(0)" ::: "memory");
    SCHEDB();
    __builtin_amdgcn_s_barrier();
    SCHEDB();

#pragma unroll
    for (int kk = 0; kk < 2; ++kk) {
      short8 bq[4];
#pragma unroll
      for (int n = 0; n < 4; ++n) {
        int col = wn * 64 + n * 16 + rA;
        int ks = (kk * 4 + kg) ^ (col & 7);
        bq[n] = *reinterpret_cast<const short8*>((const char*)Bs[b] + col * 128 + ks * 16);
      }
#pragma unroll
      for (int mh = 0; mh < 2; ++mh) {
        short8 af[4];
#pragma unroll
        for (int m = 0; m < 4; ++m) {
          int row = wm * 128 + (mh * 4 + m) * 16 + rA;
          int ks = (kk * 4 + kg) ^ (row & 7);
          af[m] = *reinterpret_cast<const short8*>((const char*)As[b] + row * 128 + ks * 16);
        }
        __builtin_amdgcn_s_setprio(1);
#pragma unroll
        for (int m = 0; m < 4; ++m)
#pragma unroll
          for (int n = 0; n < 4; ++n)
            acc[mh * 4 + m][n] =
                __builtin_amdgcn_mfma_f32_16x16x32_bf16(af[m], bq[n], acc[mh * 4 + m][n], 0, 0, 0);
        __builtin_amdgcn_s_setprio(0);
      }
    }
    asm volatile("s_waitcnt lgkmcnt(0)" ::: "memory");
    SCHEDB();
    __builtin_amdgcn_s_barrier();
    SCHEDB();
    if (t + 2 < nt) stage(t + 2, b);
  }

#pragma unroll
  for (int f = 0; f < 8; ++f) {
    int gr0 = m0 + wm * 128 + f * 16 + kg * 4;
#pragma unroll
    for (int n = 0; n < 4; ++n) {
      int gc = n0 + wn * 64 + n * 16 + rA;
      float bv = bias[gc];
#pragma unroll
      for (int r = 0; r < 4; ++r) {
        int gr = gr0 + r;
        if (gr < M) {
          float v = acc[f][n][r] + bv;
          if (ACT == 1) v = gelu_exact(v);
          if (RES == 1) v += R32[(size_t)gr * Nc + gc];
          if (RES == 2) v += bf2f(Rbf[(size_t)gr * Nc + gc]);
          if (W32) C32[(size_t)gr * Nc + gc] = v;
          if (WBF) Cbf[(size_t)gr * Nc + gc] = f2bf(v);
          if (OP) {
            if ((rA & 3) == 2) {
              float iv = 1.0f / (1.0f + v * v);
              float* op = Op + (size_t)gr * 256 + ((gc >> 2) << 1);
              op[0] = (v * v - 1.0f) * iv;
              op[1] = 2.0f * v * iv;
            }
          }
        }
      }
    }
  }
}

// ---------------- mean aggregation over bf16 rows (one wave per node; proven) ----------------
template<int W, bool ROT>
__global__ __launch_bounds__(256)
void k_agg(const unsigned short* __restrict__ X, const int* __restrict__ rp,
           const int* __restrict__ srcs, const float* __restrict__ o,
           unsigned short* __restrict__ out, int Nn) {
  int wid = (blockIdx.x * 256 + threadIdx.x) >> 6;
  int lane = threadIdx.x & 63;
  if (wid >= Nn) return;
  constexpr int PE = W / 64;
  float a[PE];
#pragma unroll
  for (int p = 0; p < PE; ++p) a[p] = 0.f;
  int beg = rp[wid], end = rp[wid + 1];
  for (int e = beg; e < end; ++e) {
    int s = srcs[e];
    const unsigned* row = reinterpret_cast<const unsigned*>(X + (size_t)s * W) + lane * (PE / 2);
    if (PE == 8) {
      uint4 v = *reinterpret_cast<const uint4*>(row);
      a[0] += bflo(v.x); a[1] += bfhi(v.x); a[2] += bflo(v.y); a[3] += bfhi(v.y);
      a[4] += bflo(v.z); a[5] += bfhi(v.z); a[6] += bflo(v.w); a[7] += bfhi(v.w);
    } else {
      uint2 v = *reinterpret_cast<const uint2*>(row);
      a[0] += bflo(v.x); a[1] += bfhi(v.x); a[2] += bflo(v.y); a[3] += bfhi(v.y);
    }
  }
  float inv = (end > beg) ? 1.0f / (float)(end - beg) : 0.0f;
#pragma unroll
  for (int p = 0; p < PE; ++p) a[p] *= inv;
  if (ROT) {
    float4 oc = *reinterpret_cast<const float4*>(o + (size_t)wid * 256 + lane * 4);
    float m0 = oc.x * a[0] - oc.y * a[1];
    float m1 = oc.y * a[0] + oc.x * a[1];
    float m2 = oc.z * a[2] - oc.w * a[3];
    float m3 = oc.w * a[2] + oc.z * a[3];
    a[0] = m0; a[1] = m1; a[2] = m2; a[3] = m3;
  }
  unsigned short* op = out + (size_t)wid * W + lane * PE;
  if (PE == 8) {
    uint4 rv;
    rv.x = packbf(a[0], a[1]); rv.y = packbf(a[2], a[3]);
    rv.z = packbf(a[4], a[5]); rv.w = packbf(a[6], a[7]);
    *reinterpret_cast<uint4*>(op) = rv;
  } else {
    uint2 rv;
    rv.x = packbf(a[0], a[1]); rv.y = packbf(a[2], a[3]);
    *reinterpret_cast<uint2*>(op) = rv;
  }
}

// ---------------- LayerNorm + rotate-into-frame; bf16 outputs ----------------
__global__ __launch_bounds__(256)
void k_ln_rot(const float* __restrict__ h, const float* __restrict__ o,
              const float* __restrict__ g, const float* __restrict__ b,
              unsigned short* __restrict__ hn, unsigned short* __restrict__ y, int Nn) {
  int wid = (blockIdx.x * 256 + threadIdx.x) >> 6;
  int lane = threadIdx.x & 63;
  if (wid >= Nn) return;
  float4 v = reinterpret_cast<const float4*>(h + (size_t)wid * 256)[lane];
  float s = v.x + v.y + v.z + v.w;
  float ss = v.x * v.x + v.y * v.y + v.z * v.z + v.w * v.w;
#pragma unroll
  for (int off = 1; off < 64; off <<= 1) { s += __shfl_xor(s, off); ss += __shfl_xor(ss, off); }
  float mean = s * (1.0f / 256.0f);
  float var = ss * (1.0f / 256.0f) - mean * mean;
  float rs = rsqrtf(var + 1e-5f);
  float4 gg = reinterpret_cast<const float4*>(g)[lane];
  float4 bb = reinterpret_cast<const float4*>(b)[lane];
  float h0 = (v.x - mean) * rs * gg.x + bb.x;
  float h1 = (v.y - mean) * rs * gg.y + bb.y;
  float h2 = (v.z - mean) * rs * gg.z + bb.z;
  float h3 = (v.w - mean) * rs * gg.w + bb.w;
  uint2 hv; hv.x = packbf(h0, h1); hv.y = packbf(h2, h3);
  *reinterpret_cast<uint2*>(hn + (size_t)wid * 256 + lane * 4) = hv;
  float4 oc = *reinterpret_cast<const float4*>(o + (size_t)wid * 256 + lane * 4);
  float y0 =  oc.x * h0 + oc.y * h1;
  float y1 = -oc.y * h0 + oc.x * h1;
  float y2 =  oc.z * h2 + oc.w * h3;
  float y3 = -oc.w * h2 + oc.z * h3;
  uint2 yv; yv.x = packbf(y0, y1); yv.y = packbf(y2, y3);
  *reinterpret_cast<uint2*>(y + (size_t)wid * 256 + lane * 4) = yv;
}

// ---------------- final: out = LN(h) @ w_out + b_out ----------------
__global__ __launch_bounds__(256)
void k_final(const float* __restrict__ h, const float* __restrict__ g,
             const float* __restrict__ b, const float* __restrict__ wout,
             const float* __restrict__ bout, float* __restrict__ out, int Nn) {
  int wid = (blockIdx.x * 256 + threadIdx.x) >> 6;
  int lane = threadIdx.x & 63;
  if (wid >= Nn) return;
  float4 v = reinterpret_cast<const float4*>(h + (size_t)wid * 256)[lane];
  float s = v.x + v.y + v.z + v.w;
  float ss = v.x * v.x + v.y * v.y + v.z * v.z + v.w * v.w;
#pragma unroll
  for (int off = 1; off < 64; off <<= 1) { s += __shfl_xor(s, off); ss += __shfl_xor(ss, off); }
  float mean = s * (1.0f / 256.0f);
  float var = ss * (1.0f / 256.0f) - mean * mean;
  float rs = rsqrtf(var + 1e-5f);
  float4 gg = reinterpret_cast<const float4*>(g)[lane];
  float4 bb = reinterpret_cast<const float4*>(b)[lane];
  float hv[4];
  hv[0] = (v.x - mean) * rs * gg.x + bb.x;
  hv[1] = (v.y - mean) * rs * gg.y + bb.y;
  hv[2] = (v.z - mean) * rs * gg.z + bb.z;
  hv[3] = (v.w - mean) * rs * gg.w + bb.w;
  int c0 = lane * 4;
  float dots[5];
#pragma unroll
  for (int j = 0; j < 5; ++j) {
    float p = hv[0] * wout[(size_t)(c0 + 0) * 5 + j] + hv[1] * wout[(size_t)(c0 + 1) * 5 + j]
            + hv[2] * wout[(size_t)(c0 + 2) * 5 + j] + hv[3] * wout[(size_t)(c0 + 3) * 5 + j];
#pragma unroll
    for (int off = 1; off < 64; off <<= 1) p += __shfl_xor(p, off);
    dots[j] = p;
  }
  if (lane == 0) {
#pragma unroll
    for (int j = 0; j < 5; ++j) out[(size_t)wid * 5 + j] = dots[j] + bout[j];
  }
}

// ---------------- host-side launch ----------------
extern "C" void kernel_launch(void* const* d_in, const int* in_sizes, int n_in,
                              void* d_out, int out_size, void* d_ws, size_t ws_size,
                              hipStream_t stream) {
  const float* x       = (const float*)d_in[0];
  const int*   ei      = (const int*)  d_in[1];
  const float* w_in    = (const float*)d_in[2];
  const float* b_in    = (const float*)d_in[3];
  const float* se_in_w = (const float*)d_in[4];
  const float* se_in_b = (const float*)d_in[5];
  const float* sage_w1 = (const float*)d_in[6];
  const float* sage_b1 = (const float*)d_in[7];
  const float* sage_w2 = (const float*)d_in[8];
  const float* sage_b2 = (const float*)d_in[9];
  const float* se_out_w= (const float*)d_in[10];
  const float* se_out_b= (const float*)d_in[11];
  const float* enc_w1  = (const float*)d_in[12];
  const float* enc_b1  = (const float*)d_in[13];
  const float* enc_w2  = (const float*)d_in[14];
  const float* enc_b2  = (const float*)d_in[15];
  const float* ln_g    = (const float*)d_in[16];
  const float* ln_b    = (const float*)d_in[17];
  const float* bdl_w1  = (const float*)d_in[18];
  const float* bdl_b1  = (const float*)d_in[19];
  const float* bdl_w2  = (const float*)d_in[20];
  const float* bdl_b2  = (const float*)d_in[21];
  const float* oln_g   = (const float*)d_in[22];
  const float* oln_b   = (const float*)d_in[23];
  const float* w_out   = (const float*)d_in[24];
  const float* b_out   = (const float*)d_in[25];
  float* out = (float*)d_out;

  const int HID = 256, SW = 512;
  const int N = in_sizes[0] / HID;   // 30000
  const int E = in_sizes[1] / 2;     // 480000

  // ---- workspace layout (~187 MB) ----
  float* ws = (float*)d_ws;
  float* h32 = ws;                              // [N,256] fp32 residual carrier
  float* o   = h32 + (size_t)N * HID;           // [N,256] rotation (c,s)*128
  unsigned short* h_bf = (unsigned short*)(o + (size_t)N * HID);  // [N,256]
  unsigned short* z_bf = h_bf + (size_t)N * HID;                  // [N,512]
  unsigned short* t_bf = z_bf + (size_t)N * SW;                   // [N,512]
  unsigned short* u_bf = t_bf + (size_t)N * SW;                   // [N,512]
  unsigned short* wts = u_bf + (size_t)N * SW;
  size_t off = 0;
  unsigned short* wt_in    = wts + off; off += 256 * 256;
  unsigned short* wt_se_in = wts + off; off += 512 * 256;
  unsigned short* wt_sage1 = wts + off; off += (size_t)5 * 512 * 1024;
  unsigned short* wt_sage2 = wts + off; off += (size_t)5 * 512 * 512;
  unsigned short* so_bf    = wts + off; off += 512 * 512;          // cast(se_out_w), native layout
  unsigned short* wt_enc1  = wts + off; off += (size_t)2 * 512 * 512;
  unsigned short* wt_enc2  = wts + off; off += (size_t)2 * 512 * 512;
  unsigned short* wt_bdl1  = wts + off; off += (size_t)2 * 256 * 512;
  unsigned short* wt_bdl2  = wts + off; off += (size_t)2 * 256 * 256;
  unsigned short* wt_f     = wts + off; off += (size_t)2 * 512 * 512; // fused se_out@enc1
  float* bf_f = (float*)(wts + off); off += 2 * 512 * 2;              // fused bias [2][512]
  float* zb   = (float*)(wts + off); off += 512 * 2;                  // zero bias
  int* deg  = (int*)(wts + off);
  int* rp   = deg + N;
  int* cur  = rp + N + 1;
  int* srcs = cur + N;
  size_t need = (size_t)((char*)(srcs + E) - (char*)d_ws);
  if (ws_size < need) return;

  // aliases (lifetime-disjoint)
  unsigned short* xbf = u_bf;
  unsigned short* hn  = z_bf;
  unsigned short* y   = z_bf + (size_t)N * HID;
  unsigned short* msg = t_bf;
  unsigned short* g2  = u_bf;

  const int* esrc = ei;
  const int* edst = ei + E;

  auto cdiv = [](int a, int b) { return (a + b - 1) / b; };
  dim3 blk(256);
  dim3 blk512(512);
  // 128^2 grids (Nc=256)
  int mb128 = cdiv(N, 128), mg128 = cdiv(mb128, 8);
  int g128_n256 = mg128 * 8 * 2;                // 480
  // 256^2 grids (Nc=512)
  int mb256 = cdiv(N, 256), mg256 = cdiv(mb256, 8);
  int g256_n512 = mg256 * 8 * 2;                // 240
  int gF = 1 * 8 * 2;                            // M=512 F-GEMM grid
  int gw = cdiv(N * 64, 256);

  // ---- CSR build ----
  hipMemsetAsync(deg, 0, sizeof(int) * N, stream);
  k_hist<<<cdiv(E, 256), blk, 0, stream>>>(edst, deg, E);
  k_scan<<<1, 1024, 0, stream>>>(deg, rp, cur, N);
  k_fill<<<cdiv(E, 256), blk, 0, stream>>>(esrc, edst, cur, srcs, E);

  // ---- weight prep ----
  auto wT = [&](const float* W, unsigned short* Wt, int K, int Nc, int cnt) {
    k_wT<<<dim3(cdiv(K * Nc, 256), cnt), blk, 0, stream>>>(W, Wt, K, Nc);
  };
  wT(w_in, wt_in, 256, 256, 1);
  wT(se_in_w, wt_se_in, 256, 512, 1);
  wT(sage_w1, wt_sage1, 1024, 512, 5);
  wT(sage_w2, wt_sage2, 512, 512, 5);
  wT(enc_w1, wt_enc1, 512, 512, 2);
  wT(enc_w2, wt_enc2, 512, 512, 2);
  wT(bdl_w1, wt_bdl1, 512, 256, 2);
  wT(bdl_w2, wt_bdl2, 256, 256, 2);
  k_cast<<<cdiv(512 * 512, 256), blk, 0, stream>>>(se_out_w, so_bf, 512 * 512);
  k_cast<<<cdiv(N * HID, 256), blk, 0, stream>>>(x, xbf, N * HID);
  hipMemsetAsync(zb, 0, 512 * sizeof(float), stream);
  k_bfuse<<<dim3(2, 2), blk, 0, stream>>>(se_out_b, enc_w1, enc_b1, bf_f);
  // F_k = se_out_w @ enc_w1[k]  ->  wt_f[k][n_u][j_z]  (A=wt_enc1[k], Wt=so_bf)
  for (int k = 0; k < 2; ++k)
    k_mfma256<0, 0, false, false, true, false><<<gF, blk512, 0, stream>>>(
        wt_enc1 + (size_t)k * 512 * 512, nullptr, 512, 0, so_bf, zb,
        nullptr, nullptr, nullptr, wt_f + (size_t)k * 512 * 512, nullptr, 512, 512);

  // ---- h = gelu(x @ w_in + b_in) : fp32 + bf16 ----
  k_mfma<1, 0, false, true, true><<<g128_n256, blk, 0, stream>>>(
      xbf, nullptr, 256, 0, wt_in, b_in, nullptr, nullptr, h32, h_bf, N, 256);

  for (int k = 0; k < 2; ++k) {
    // z = gelu(h @ se_in_w + b)
    k_mfma256<1, 0, false, false, true, false><<<g256_n512, blk512, 0, stream>>>(
        h_bf, nullptr, 256, 0, wt_se_in, se_in_b, nullptr, nullptr, nullptr, z_bf, nullptr, N, 512);
    for (int i = 0; i < 5; ++i) {
      k_agg<512, false><<<gw, blk, 0, stream>>>(z_bf, rp, srcs, nullptr, t_bf, N);
      k_mfma256<1, 0, true, false, true, false><<<g256_n512, blk512, 0, stream>>>(
          z_bf, t_bf, 512, 512, wt_sage1 + (size_t)i * 512 * 1024,
          sage_b1 + (size_t)i * SW, nullptr, nullptr, nullptr, u_bf, nullptr, N, 512);
      k_mfma256<0, 2, false, false, true, false><<<g256_n512, blk512, 0, stream>>>(
          u_bf, nullptr, 512, 0, wt_sage2 + (size_t)i * 512 * 512,
          sage_b2 + (size_t)i * SW, nullptr, z_bf, nullptr, z_bf, nullptr, N, 512);
    }
    // u = gelu(z @ F_k + bf_k)   (se_out folded into enc1)
    k_mfma256<1, 0, false, false, true, false><<<g256_n512, blk512, 0, stream>>>(
        z_bf, nullptr, 512, 0, wt_f + (size_t)k * 512 * 512,
        bf_f + (size_t)k * 512, nullptr, nullptr, nullptr, u_bf, nullptr, N, 512);
    // nr = u @ enc_w2 + b ; rotation params fused (only o written)
    k_mfma256<0, 0, false, false, false, true><<<g256_n512, blk512, 0, stream>>>(
        u_bf, nullptr, 512, 0, wt_enc2 + (size_t)k * 512 * 512,
        enc_b2 + (size_t)k * SW, nullptr, nullptr, nullptr, nullptr, o, N, 512);
    // hn=LN(h), y=O@hn; msg=O^T@mean(y)
    k_ln_rot<<<gw, blk, 0, stream>>>(h32, o, ln_g + (size_t)k * HID, ln_b + (size_t)k * HID, hn, y, N);
    k_agg<256, true><<<gw, blk, 0, stream>>>(y, rp, srcs, o, msg, N);
    // h = h + gelu([hn|msg] @ bdl_w1 + b1) @ bdl_w2 + b2
    k_mfma<1, 0, true, false, true><<<g128_n256, blk, 0, stream>>>(
        hn, msg, 256, 256, wt_bdl1 + (size_t)k * 256 * 512,
        bdl_b1 + (size_t)k * HID, nullptr, nullptr, nullptr, g2, N, 256);
    k_mfma<0, 1, false, true, true><<<g128_n256, blk, 0, stream>>>(
        g2, nullptr, 256, 0, wt_bdl2 + (size_t)k * 256 * 256,
        bdl_b2 + (size_t)k * HID, h32, nullptr, h32, h_bf, N, 256);
  }

  k_final<<<gw, blk, 0, stream>>>(h32, oln_g, oln_b, w_out, b_out, out, N);
}

// Round 11
// 2498.683 us; speedup vs baseline: 1.0669x; 1.0669x over previous
//
#include <hip/hip_runtime.h>
#include <hip/hip_bf16.h>
#include <cstdint>
#include <cstddef>

// N=30000 nodes, E=480000 edges, HID=256, SW=512, NB=128 bundles of dim 2.
// Householder(2x2) collapses to planar rotation: x=X[1,0]; c=(x^2-1)/(1+x^2), s=2x/(1+x^2).
// enc feeds only enc_w1 => se_out GEMM eliminated via F_k = se_out_w @ enc_w1[k].

typedef __attribute__((ext_vector_type(8))) short short8;
typedef __attribute__((ext_vector_type(4))) float f32x4;

__device__ __forceinline__ float gelu_exact(float x) {
  return 0.5f * x * (1.0f + erff(x * 0.7071067811865475f));
}
__device__ __forceinline__ unsigned short f2bf(float f) {
  __hip_bfloat16 b = __float2bfloat16(f);
  return *reinterpret_cast<unsigned short*>(&b);
}
__device__ __forceinline__ float bf2f(unsigned short u) {
  return __uint_as_float((unsigned)u << 16);
}
__device__ __forceinline__ float bflo(unsigned u) { return __uint_as_float(u << 16); }
__device__ __forceinline__ float bfhi(unsigned u) { return __uint_as_float(u & 0xffff0000u); }
__device__ __forceinline__ unsigned packbf(float f0, float f1) {
  return (unsigned)f2bf(f0) | ((unsigned)f2bf(f1) << 16);
}
__device__ __forceinline__ void gload16(const void* g, void* l) {
  __builtin_amdgcn_global_load_lds((const __attribute__((address_space(1))) void*)g,
                                   (__attribute__((address_space(3))) void*)l, 16, 0, 0);
}
#define SCHEDB() __builtin_amdgcn_sched_barrier(0)

// ---------------- CSR build ----------------
__global__ void k_hist(const int* __restrict__ dst, int* __restrict__ deg, int E) {
  int i = blockIdx.x * 256 + threadIdx.x;
  if (i < E) atomicAdd(&deg[dst[i]], 1);
}

__global__ __launch_bounds__(1024)
void k_scan(const int* __restrict__ deg, int* __restrict__ rp, int* __restrict__ cur, int Nn) {
  __shared__ int part[1024];
  int t = threadIdx.x;
  int chunk = (Nn + 1023) >> 10;
  int s0 = t * chunk;
  int e0 = s0 + chunk; if (e0 > Nn) e0 = Nn;
  int s = 0;
  for (int i = s0; i < e0; ++i) s += deg[i];
  part[t] = s;
  __syncthreads();
  for (int off = 1; off < 1024; off <<= 1) {
    int v = (t >= off) ? part[t - off] : 0;
    __syncthreads();
    part[t] += v;
    __syncthreads();
  }
  int base = (t == 0) ? 0 : part[t - 1];
  for (int i = s0; i < e0; ++i) {
    rp[i] = base; cur[i] = base; base += deg[i];
  }
  if (t == 0) rp[Nn] = part[1023];
}

__global__ void k_fill(const int* __restrict__ src, const int* __restrict__ dst,
                       int* __restrict__ cur, int* __restrict__ srcs, int E) {
  int i = blockIdx.x * 256 + threadIdx.x;
  if (i < E) {
    int p = atomicAdd(&cur[dst[i]], 1);
    srcs[p] = src[i];
  }
}

// ---------------- batched weight transpose fp32 [K,N] -> bf16 [N,K] ----------------
__global__ void k_wT(const float* __restrict__ W, unsigned short* __restrict__ Wt, int K, int Nc) {
  const float* Ws = W + (size_t)blockIdx.y * K * Nc;
  unsigned short* Wd = Wt + (size_t)blockIdx.y * K * Nc;
  int idx = blockIdx.x * 256 + threadIdx.x;
  if (idx >= K * Nc) return;
  int k = idx % K, n = idx / K;                       // k fastest -> coalesced writes
  Wd[(size_t)n * K + k] = f2bf(Ws[(size_t)k * Nc + n]);
}

__global__ void k_cast(const float* __restrict__ src, unsigned short* __restrict__ dst, int n) {
  int i = blockIdx.x * 256 + threadIdx.x;
  if (i < n) dst[i] = f2bf(src[i]);
}

// fused bias: bf[k][n] = sum_e b_so[e]*enc_w1[k][e][n] + b_e1[k][n]
__global__ void k_bfuse(const float* __restrict__ b_so, const float* __restrict__ W_e1,
                        const float* __restrict__ b_e1, float* __restrict__ bf) {
  int k = blockIdx.y;
  int n = blockIdx.x * 256 + threadIdx.x;
  if (n >= 512) return;
  const float* W = W_e1 + (size_t)k * 512 * 512;
  float s = b_e1[(size_t)k * 512 + n];
  for (int e = 0; e < 512; ++e) s += b_so[e] * W[(size_t)e * 512 + n];
  bf[(size_t)k * 512 + n] = s;
}

// ---------------- bf16 MFMA GEMM: 128x128 tile, BK=64, 4 waves, double-buffered ----------------
// C = [R +] act(A @ W + bias), A bf16 row-major (dual-source concat along K),
// Wt = W^T bf16 [Nc, Ktot] row-major. fp32 accumulate. 64 KiB LDS -> 2 blocks/CU.
// Depth-2 counted-vmcnt schedule (proven round 9); XCD co-location via padded 1D grid.
// RES: 0=none, 1=fp32 residual, 2=bf16 residual. OP: emit rotation params from nr output.
template<int ACT, int RES, bool DUAL, bool W32, bool WBF, bool OP>
__global__ __launch_bounds__(256)
void k_mfma(const unsigned short* __restrict__ A1, const unsigned short* __restrict__ A2,
            int K1, int K2,
            const unsigned short* __restrict__ Wt, const float* __restrict__ bias,
            const float* R32, const unsigned short* Rbf,
            float* C32, unsigned short* Cbf, float* Op, int M, int Nc) {
  const int mb_cnt = (M + 127) >> 7;
  const int nb_cnt = Nc >> 7;
  int u = blockIdx.x;
  int xcd = u & 7;
  int rest = u >> 3;
  int nb = rest % nb_cnt;
  int mb = (rest / nb_cnt) * 8 + xcd;
  if (mb >= mb_cnt) return;
  const int m0 = mb << 7, n0 = nb << 7;

  __shared__ unsigned short As[2][128 * 64];   // [buf][row][64] bf16, 128B rows, swizzled segs
  __shared__ unsigned short Bs[2][128 * 64];
  const int tid = threadIdx.x;
  const int lane = tid & 63, wv = tid >> 6;
  const int wr = (wv >> 1) * 64, wc = (wv & 1) * 64;  // wave's 64x64 subtile
  const int rA = lane & 15, kg = lane >> 4;
  const int Ktot = K1 + K2;
  const int nt = Ktot >> 6;

  f32x4 acc[4][4];
#pragma unroll
  for (int m = 0; m < 4; ++m)
#pragma unroll
    for (int n = 0; n < 4; ++n)
#pragma unroll
      for (int r = 0; r < 4; ++r) acc[m][n][r] = 0.f;

  // stage K-tile t into buffer b: 1024 16B-chunks per matrix, 4 issues x 256 thr.
  // linear LDS dest; swizzle applied on the GLOBAL source k-segment (involution).
  auto stage = [&](int t, int b) {
    int k0 = t << 6;
    const unsigned short* Asrc; int kc, lda;
    if (!DUAL || k0 < K1) { Asrc = A1; kc = k0; lda = K1; }
    else                  { Asrc = A2; kc = k0 - K1; lda = K2; }
#pragma unroll
    for (int is = 0; is < 4; ++is) {
      int chunk = is * 256 + tid;
      int row = chunk >> 3, seg = chunk & 7;
      int ks = seg ^ (row & 7);
      int gm = m0 + row; gm = gm < M ? gm : M - 1;
      gload16(Asrc + (size_t)gm * lda + kc + ks * 8, (char*)As[b] + (size_t)chunk * 16);
      gload16(Wt + (size_t)(n0 + row) * Ktot + k0 + ks * 8, (char*)Bs[b] + (size_t)chunk * 16);
    }
  };

  stage(0, 0);
  if (nt > 1) stage(1, 1);

  for (int t = 0; t < nt; ++t) {
    const int b = t & 1;
    // tile t's own loads complete; tile t+1's 8 loads may stay in flight
    if (t + 1 < nt) asm volatile("s_waitcnt vmcnt(8)" ::: "memory");
    else            asm volatile("s_waitcnt vmcnt(0)" ::: "memory");
    SCHEDB();
    __builtin_amdgcn_s_barrier();
    SCHEDB();

    short8 af[2][4], bq[2][4];
#pragma unroll
    for (int kk = 0; kk < 2; ++kk) {
#pragma unroll
      for (int m = 0; m < 4; ++m) {
        int row = wr + m * 16 + rA;
        int ks = (kk * 4 + kg) ^ (row & 7);
        af[kk][m] = *reinterpret_cast<const short8*>((const char*)As[b] + row * 128 + ks * 16);
      }
#pragma unroll
      for (int n = 0; n < 4; ++n) {
        int col = wc + n * 16 + rA;
        int ks = (kk * 4 + kg) ^ (col & 7);
        bq[kk][n] = *reinterpret_cast<const short8*>((const char*)Bs[b] + col * 128 + ks * 16);
      }
    }
    asm volatile("s_waitcnt lgkmcnt(0)" ::: "memory");
    SCHEDB();
    __builtin_amdgcn_s_barrier();   // all waves done reading buf b
    SCHEDB();
    if (t + 2 < nt) stage(t + 2, b);  // DMA into freed buffer, overlaps MFMA

    __builtin_amdgcn_s_setprio(1);
#pragma unroll
    for (int kk = 0; kk < 2; ++kk)
#pragma unroll
      for (int m = 0; m < 4; ++m)
#pragma unroll
        for (int n = 0; n < 4; ++n)
          acc[m][n] = __builtin_amdgcn_mfma_f32_16x16x32_bf16(af[kk][m], bq[kk][n],
                                                              acc[m][n], 0, 0, 0);
    __builtin_amdgcn_s_setprio(0);
  }

  // epilogue: C/D layout col=lane&15, row=(lane>>4)*4+reg  [m89]
#pragma unroll
  for (int m = 0; m < 4; ++m) {
    int gr0 = m0 + wr + m * 16 + kg * 4;
#pragma unroll
    for (int n = 0; n < 4; ++n) {
      int gc = n0 + wc + n * 16 + rA;
      float bv = bias[gc];
#pragma unroll
      for (int r = 0; r < 4; ++r) {
        int gr = gr0 + r;
        if (gr < M) {
          float v = acc[m][n][r] + bv;
          if (ACT == 1) v = gelu_exact(v);
          if (RES == 1) v += R32[(size_t)gr * Nc + gc];
          if (RES == 2) v += bf2f(Rbf[(size_t)gr * Nc + gc]);
          if (W32) C32[(size_t)gr * Nc + gc] = v;
          if (WBF) Cbf[(size_t)gr * Nc + gc] = f2bf(v);
          if (OP) {
            // nr column 4b+2 -> rotation (c,s) for bundle b = gc>>2
            if ((rA & 3) == 2) {
              float iv = 1.0f / (1.0f + v * v);
              float* op = Op + (size_t)gr * 256 + ((gc >> 2) << 1);
              op[0] = (v * v - 1.0f) * iv;
              op[1] = 2.0f * v * iv;
            }
          }
        }
      }
    }
  }
}

// ---------------- mean aggregation, edge-unrolled x4 for memory-level parallelism ----------------
// One wave per node; lane owns PE contiguous bf16 columns. 4 independent 1KB gathers
// in flight per iteration (was 1 -> latency-bound at ~94 cy/gather).
template<int W, bool ROT>
__global__ __launch_bounds__(256)
void k_agg(const unsigned short* __restrict__ X, const int* __restrict__ rp,
           const int* __restrict__ srcs, const float* __restrict__ o,
           unsigned short* __restrict__ out, int Nn) {
  int wid = (blockIdx.x * 256 + threadIdx.x) >> 6;
  int lane = threadIdx.x & 63;
  if (wid >= Nn) return;
  constexpr int PE = W / 64;    // bf16 elems per lane: 8 (W=512) or 4 (W=256)
  float a[PE];
#pragma unroll
  for (int p = 0; p < PE; ++p) a[p] = 0.f;
  int beg = rp[wid], end = rp[wid + 1];
  int e = beg;
  if (PE == 8) {
    for (; e + 4 <= end; e += 4) {
      int s0 = srcs[e], s1 = srcs[e + 1], s2 = srcs[e + 2], s3 = srcs[e + 3];
      uint4 v0 = *reinterpret_cast<const uint4*>(X + (size_t)s0 * W + lane * 8);
      uint4 v1 = *reinterpret_cast<const uint4*>(X + (size_t)s1 * W + lane * 8);
      uint4 v2 = *reinterpret_cast<const uint4*>(X + (size_t)s2 * W + lane * 8);
      uint4 v3 = *reinterpret_cast<const uint4*>(X + (size_t)s3 * W + lane * 8);
      a[0] += bflo(v0.x) + bflo(v1.x) + bflo(v2.x) + bflo(v3.x);
      a[1] += bfhi(v0.x) + bfhi(v1.x) + bfhi(v2.x) + bfhi(v3.x);
      a[2] += bflo(v0.y) + bflo(v1.y) + bflo(v2.y) + bflo(v3.y);
      a[3] += bfhi(v0.y) + bfhi(v1.y) + bfhi(v2.y) + bfhi(v3.y);
      a[4] += bflo(v0.z) + bflo(v1.z) + bflo(v2.z) + bflo(v3.z);
      a[5] += bfhi(v0.z) + bfhi(v1.z) + bfhi(v2.z) + bfhi(v3.z);
      a[6] += bflo(v0.w) + bflo(v1.w) + bflo(v2.w) + bflo(v3.w);
      a[7] += bfhi(v0.w) + bfhi(v1.w) + bfhi(v2.w) + bfhi(v3.w);
    }
    for (; e < end; ++e) {
      int s = srcs[e];
      uint4 v = *reinterpret_cast<const uint4*>(X + (size_t)s * W + lane * 8);
      a[0] += bflo(v.x); a[1] += bfhi(v.x); a[2] += bflo(v.y); a[3] += bfhi(v.y);
      a[4] += bflo(v.z); a[5] += bfhi(v.z); a[6] += bflo(v.w); a[7] += bfhi(v.w);
    }
  } else {
    for (; e + 4 <= end; e += 4) {
      int s0 = srcs[e], s1 = srcs[e + 1], s2 = srcs[e + 2], s3 = srcs[e + 3];
      uint2 v0 = *reinterpret_cast<const uint2*>(X + (size_t)s0 * W + lane * 4);
      uint2 v1 = *reinterpret_cast<const uint2*>(X + (size_t)s1 * W + lane * 4);
      uint2 v2 = *reinterpret_cast<const uint2*>(X + (size_t)s2 * W + lane * 4);
      uint2 v3 = *reinterpret_cast<const uint2*>(X + (size_t)s3 * W + lane * 4);
      a[0] += bflo(v0.x) + bflo(v1.x) + bflo(v2.x) + bflo(v3.x);
      a[1] += bfhi(v0.x) + bfhi(v1.x) + bfhi(v2.x) + bfhi(v3.x);
      a[2] += bflo(v0.y) + bflo(v1.y) + bflo(v2.y) + bflo(v3.y);
      a[3] += bfhi(v0.y) + bfhi(v1.y) + bfhi(v2.y) + bfhi(v3.y);
    }
    for (; e < end; ++e) {
      int s = srcs[e];
      uint2 v = *reinterpret_cast<const uint2*>(X + (size_t)s * W + lane * 4);
      a[0] += bflo(v.x); a[1] += bfhi(v.x); a[2] += bflo(v.y); a[3] += bfhi(v.y);
    }
  }
  float inv = (end > beg) ? 1.0f / (float)(end - beg) : 0.0f;
#pragma unroll
  for (int p = 0; p < PE; ++p) a[p] *= inv;
  if (ROT) {
    float4 oc = *reinterpret_cast<const float4*>(o + (size_t)wid * 256 + lane * 4); // c0,s0,c1,s1
    float m0 = oc.x * a[0] - oc.y * a[1];
    float m1 = oc.y * a[0] + oc.x * a[1];
    float m2 = oc.z * a[2] - oc.w * a[3];
    float m3 = oc.w * a[2] + oc.z * a[3];
    a[0] = m0; a[1] = m1; a[2] = m2; a[3] = m3;
  }
  unsigned short* op = out + (size_t)wid * W + lane * PE;
  if (PE == 8) {
    uint4 rv;
    rv.x = packbf(a[0], a[1]); rv.y = packbf(a[2], a[3]);
    rv.z = packbf(a[4], a[5]); rv.w = packbf(a[6], a[7]);
    *reinterpret_cast<uint4*>(op) = rv;
  } else {
    uint2 rv;
    rv.x = packbf(a[0], a[1]); rv.y = packbf(a[2], a[3]);
    *reinterpret_cast<uint2*>(op) = rv;
  }
}

// ---------------- LayerNorm + rotate-into-frame; bf16 outputs ----------------
__global__ __launch_bounds__(256)
void k_ln_rot(const float* __restrict__ h, const float* __restrict__ o,
              const float* __restrict__ g, const float* __restrict__ b,
              unsigned short* __restrict__ hn, unsigned short* __restrict__ y, int Nn) {
  int wid = (blockIdx.x * 256 + threadIdx.x) >> 6;
  int lane = threadIdx.x & 63;
  if (wid >= Nn) return;
  float4 v = reinterpret_cast<const float4*>(h + (size_t)wid * 256)[lane];
  float s = v.x + v.y + v.z + v.w;
  float ss = v.x * v.x + v.y * v.y + v.z * v.z + v.w * v.w;
#pragma unroll
  for (int off = 1; off < 64; off <<= 1) { s += __shfl_xor(s, off); ss += __shfl_xor(ss, off); }
  float mean = s * (1.0f / 256.0f);
  float var = ss * (1.0f / 256.0f) - mean * mean;
  float rs = rsqrtf(var + 1e-5f);
  float4 gg = reinterpret_cast<const float4*>(g)[lane];
  float4 bb = reinterpret_cast<const float4*>(b)[lane];
  float h0 = (v.x - mean) * rs * gg.x + bb.x;
  float h1 = (v.y - mean) * rs * gg.y + bb.y;
  float h2 = (v.z - mean) * rs * gg.z + bb.z;
  float h3 = (v.w - mean) * rs * gg.w + bb.w;
  uint2 hv; hv.x = packbf(h0, h1); hv.y = packbf(h2, h3);
  *reinterpret_cast<uint2*>(hn + (size_t)wid * 256 + lane * 4) = hv;
  float4 oc = *reinterpret_cast<const float4*>(o + (size_t)wid * 256 + lane * 4); // c0,s0,c1,s1
  float y0 =  oc.x * h0 + oc.y * h1;
  float y1 = -oc.y * h0 + oc.x * h1;
  float y2 =  oc.z * h2 + oc.w * h3;
  float y3 = -oc.w * h2 + oc.z * h3;
  uint2 yv; yv.x = packbf(y0, y1); yv.y = packbf(y2, y3);
  *reinterpret_cast<uint2*>(y + (size_t)wid * 256 + lane * 4) = yv;
}

// ---------------- final: out = LN(h) @ w_out + b_out ----------------
__global__ __launch_bounds__(256)
void k_final(const float* __restrict__ h, const float* __restrict__ g,
             const float* __restrict__ b, const float* __restrict__ wout,
             const float* __restrict__ bout, float* __restrict__ out, int Nn) {
  int wid = (blockIdx.x * 256 + threadIdx.x) >> 6;
  int lane = threadIdx.x & 63;
  if (wid >= Nn) return;
  float4 v = reinterpret_cast<const float4*>(h + (size_t)wid * 256)[lane];
  float s = v.x + v.y + v.z + v.w;
  float ss = v.x * v.x + v.y * v.y + v.z * v.z + v.w * v.w;
#pragma unroll
  for (int off = 1; off < 64; off <<= 1) { s += __shfl_xor(s, off); ss += __shfl_xor(ss, off); }
  float mean = s * (1.0f / 256.0f);
  float var = ss * (1.0f / 256.0f) - mean * mean;
  float rs = rsqrtf(var + 1e-5f);
  float4 gg = reinterpret_cast<const float4*>(g)[lane];
  float4 bb = reinterpret_cast<const float4*>(b)[lane];
  float hv[4];
  hv[0] = (v.x - mean) * rs * gg.x + bb.x;
  hv[1] = (v.y - mean) * rs * gg.y + bb.y;
  hv[2] = (v.z - mean) * rs * gg.z + bb.z;
  hv[3] = (v.w - mean) * rs * gg.w + bb.w;
  int c0 = lane * 4;
  float dots[5];
#pragma unroll
  for (int j = 0; j < 5; ++j) {
    float p = hv[0] * wout[(size_t)(c0 + 0) * 5 + j] + hv[1] * wout[(size_t)(c0 + 1) * 5 + j]
            + hv[2] * wout[(size_t)(c0 + 2) * 5 + j] + hv[3] * wout[(size_t)(c0 + 3) * 5 + j];
#pragma unroll
    for (int off = 1; off < 64; off <<= 1) p += __shfl_xor(p, off);
    dots[j] = p;
  }
  if (lane == 0) {
#pragma unroll
    for (int j = 0; j < 5; ++j) out[(size_t)wid * 5 + j] = dots[j] + bout[j];
  }
}

// ---------------- host-side launch ----------------
extern "C" void kernel_launch(void* const* d_in, const int* in_sizes, int n_in,
                              void* d_out, int out_size, void* d_ws, size_t ws_size,
                              hipStream_t stream) {
  const float* x       = (const float*)d_in[0];
  const int*   ei      = (const int*)  d_in[1];
  const float* w_in    = (const float*)d_in[2];
  const float* b_in    = (const float*)d_in[3];
  const float* se_in_w = (const float*)d_in[4];
  const float* se_in_b = (const float*)d_in[5];
  const float* sage_w1 = (const float*)d_in[6];
  const float* sage_b1 = (const float*)d_in[7];
  const float* sage_w2 = (const float*)d_in[8];
  const float* sage_b2 = (const float*)d_in[9];
  const float* se_out_w= (const float*)d_in[10];
  const float* se_out_b= (const float*)d_in[11];
  const float* enc_w1  = (const float*)d_in[12];
  const float* enc_b1  = (const float*)d_in[13];
  const float* enc_w2  = (const float*)d_in[14];
  const float* enc_b2  = (const float*)d_in[15];
  const float* ln_g    = (const float*)d_in[16];
  const float* ln_b    = (const float*)d_in[17];
  const float* bdl_w1  = (const float*)d_in[18];
  const float* bdl_b1  = (const float*)d_in[19];
  const float* bdl_w2  = (const float*)d_in[20];
  const float* bdl_b2  = (const float*)d_in[21];
  const float* oln_g   = (const float*)d_in[22];
  const float* oln_b   = (const float*)d_in[23];
  const float* w_out   = (const float*)d_in[24];
  const float* b_out   = (const float*)d_in[25];
  float* out = (float*)d_out;

  const int HID = 256, SW = 512;
  const int N = in_sizes[0] / HID;   // 30000
  const int E = in_sizes[1] / 2;     // 480000

  // ---- workspace layout (~187 MB) ----
  float* ws = (float*)d_ws;
  float* h32 = ws;                              // [N,256] fp32 residual carrier
  float* o   = h32 + (size_t)N * HID;           // [N,256] rotation (c,s)*128
  unsigned short* h_bf = (unsigned short*)(o + (size_t)N * HID);  // [N,256]
  unsigned short* z_bf = h_bf + (size_t)N * HID;                  // [N,512]
  unsigned short* t_bf = z_bf + (size_t)N * SW;                   // [N,512]
  unsigned short* u_bf = t_bf + (size_t)N * SW;                   // [N,512]
  unsigned short* wts = u_bf + (size_t)N * SW;
  size_t off = 0;
  unsigned short* wt_in    = wts + off; off += 256 * 256;
  unsigned short* wt_se_in = wts + off; off += 512 * 256;
  unsigned short* wt_sage1 = wts + off; off += (size_t)5 * 512 * 1024;
  unsigned short* wt_sage2 = wts + off; off += (size_t)5 * 512 * 512;
  unsigned short* so_bf    = wts + off; off += 512 * 512;          // cast(se_out_w), native layout
  unsigned short* wt_enc1  = wts + off; off += (size_t)2 * 512 * 512;
  unsigned short* wt_enc2  = wts + off; off += (size_t)2 * 512 * 512;
  unsigned short* wt_bdl1  = wts + off; off += (size_t)2 * 256 * 512;
  unsigned short* wt_bdl2  = wts + off; off += (size_t)2 * 256 * 256;
  unsigned short* wt_f     = wts + off; off += (size_t)2 * 512 * 512; // fused se_out@enc1
  float* bf_f = (float*)(wts + off); off += 2 * 512 * 2;              // fused bias [2][512]
  float* zb   = (float*)(wts + off); off += 512 * 2;                  // zero bias
  int* deg  = (int*)(wts + off);
  int* rp   = deg + N;
  int* cur  = rp + N + 1;
  int* srcs = cur + N;
  size_t need = (size_t)((char*)(srcs + E) - (char*)d_ws);
  if (ws_size < need) return;

  // aliases (lifetime-disjoint)
  unsigned short* xbf = u_bf;
  unsigned short* hn  = z_bf;
  unsigned short* y   = z_bf + (size_t)N * HID;
  unsigned short* msg = t_bf;
  unsigned short* g2  = u_bf;

  const int* esrc = ei;
  const int* edst = ei + E;

  auto cdiv = [](int a, int b) { return (a + b - 1) / b; };
  dim3 blk(256);
  int mb_cnt = cdiv(N, 128);                    // 235
  int mgrp = cdiv(mb_cnt, 8);                   // 30
  int g_g256 = mgrp * 8 * 2;                    // Nc=256 -> 480 blocks (padded)
  int g_g512 = mgrp * 8 * 4;                    // Nc=512 -> 960 blocks (padded)
  int g_F    = 1 * 8 * 4;                       // M=512, Nc=512 -> 32 blocks (16 active)
  int gw = cdiv(N * 64, 256);

  // ---- CSR build ----
  hipMemsetAsync(deg, 0, sizeof(int) * N, stream);
  k_hist<<<cdiv(E, 256), blk, 0, stream>>>(edst, deg, E);
  k_scan<<<1, 1024, 0, stream>>>(deg, rp, cur, N);
  k_fill<<<cdiv(E, 256), blk, 0, stream>>>(esrc, edst, cur, srcs, E);

  // ---- weight prep ----
  auto wT = [&](const float* W, unsigned short* Wt, int K, int Nc, int cnt) {
    k_wT<<<dim3(cdiv(K * Nc, 256), cnt), blk, 0, stream>>>(W, Wt, K, Nc);
  };
  wT(w_in, wt_in, 256, 256, 1);
  wT(se_in_w, wt_se_in, 256, 512, 1);
  wT(sage_w1, wt_sage1, 1024, 512, 5);
  wT(sage_w2, wt_sage2, 512, 512, 5);
  wT(enc_w1, wt_enc1, 512, 512, 2);
  wT(enc_w2, wt_enc2, 512, 512, 2);
  wT(bdl_w1, wt_bdl1, 512, 256, 2);
  wT(bdl_w2, wt_bdl2, 256, 256, 2);
  k_cast<<<cdiv(512 * 512, 256), blk, 0, stream>>>(se_out_w, so_bf, 512 * 512);
  k_cast<<<cdiv(N * HID, 256), blk, 0, stream>>>(x, xbf, N * HID);
  hipMemsetAsync(zb, 0, 512 * sizeof(float), stream);
  k_bfuse<<<dim3(2, 2), blk, 0, stream>>>(se_out_b, enc_w1, enc_b1, bf_f);
  // F_k = se_out_w @ enc_w1[k] -> wt_f[k] in W^T layout (A=wt_enc1[k], Wt=so_bf); verified R10
  for (int k = 0; k < 2; ++k)
    k_mfma<0, 0, false, false, true, false><<<g_F, blk, 0, stream>>>(
        wt_enc1 + (size_t)k * 512 * 512, nullptr, 512, 0, so_bf, zb,
        nullptr, nullptr, nullptr, wt_f + (size_t)k * 512 * 512, nullptr, 512, 512);

  // ---- h = gelu(x @ w_in + b_in) : fp32 + bf16 ----
  k_mfma<1, 0, false, true, true, false><<<g_g256, blk, 0, stream>>>(
      xbf, nullptr, 256, 0, wt_in, b_in, nullptr, nullptr, h32, h_bf, nullptr, N, 256);

  for (int k = 0; k < 2; ++k) {
    // z = gelu(h @ se_in_w + b)
    k_mfma<1, 0, false, false, true, false><<<g_g512, blk, 0, stream>>>(
        h_bf, nullptr, 256, 0, wt_se_in, se_in_b, nullptr, nullptr, nullptr, z_bf, nullptr, N, 512);
    for (int i = 0; i < 5; ++i) {
      k_agg<512, false><<<gw, blk, 0, stream>>>(z_bf, rp, srcs, nullptr, t_bf, N);
      k_mfma<1, 0, true, false, true, false><<<g_g512, blk, 0, stream>>>(
          z_bf, t_bf, 512, 512, wt_sage1 + (size_t)i * 512 * 1024,
          sage_b1 + (size_t)i * SW, nullptr, nullptr, nullptr, u_bf, nullptr, N, 512);
      k_mfma<0, 2, false, false, true, false><<<g_g512, blk, 0, stream>>>(
          u_bf, nullptr, 512, 0, wt_sage2 + (size_t)i * 512 * 512,
          sage_b2 + (size_t)i * SW, nullptr, z_bf, nullptr, z_bf, nullptr, N, 512);
    }
    // u = gelu(z @ F_k + bf_k)   (se_out folded into enc1)
    k_mfma<1, 0, false, false, true, false><<<g_g512, blk, 0, stream>>>(
        z_bf, nullptr, 512, 0, wt_f + (size_t)k * 512 * 512,
        bf_f + (size_t)k * 512, nullptr, nullptr, nullptr, u_bf, nullptr, N, 512);
    // nr = u @ enc_w2 + b ; rotation params fused into epilogue (only o written)
    k_mfma<0, 0, false, false, false, true><<<g_g512, blk, 0, stream>>>(
        u_bf, nullptr, 512, 0, wt_enc2 + (size_t)k * 512 * 512,
        enc_b2 + (size_t)k * SW, nullptr, nullptr, nullptr, nullptr, o, N, 512);
    // hn=LN(h), y=O@hn; msg=O^T@mean(y)
    k_ln_rot<<<gw, blk, 0, stream>>>(h32, o, ln_g + (size_t)k * HID, ln_b + (size_t)k * HID, hn, y, N);
    k_agg<256, true><<<gw, blk, 0, stream>>>(y, rp, srcs, o, msg, N);
    // h = h + gelu([hn|msg] @ bdl_w1 + b1) @ bdl_w2 + b2
    k_mfma<1, 0, true, false, true, false><<<g_g256, blk, 0, stream>>>(
        hn, msg, 256, 256, wt_bdl1 + (size_t)k * 256 * 512,
        bdl_b1 + (size_t)k * HID, nullptr, nullptr, nullptr, g2, nullptr, N, 256);
    k_mfma<0, 1, false, true, true, false><<<g_g256, blk, 0, stream>>>(
        g2, nullptr, 256, 0, wt_bdl2 + (size_t)k * 256 * 256,
        bdl_b2 + (size_t)k * HID, h32, nullptr, h32, h_bf, nullptr, N, 256);
  }

  k_final<<<gw, blk, 0, stream>>>(h32, oln_g, oln_b, w_out, b_out, out, N);
}

// Round 12
// 2439.894 us; speedup vs baseline: 1.0926x; 1.0241x over previous
//
#include <hip/hip_runtime.h>
#include <hip/hip_bf16.h>
#include <cstdint>
#include <cstddef>

// N=30000 nodes, E=480000 edges, HID=256, SW=512, NB=128 bundles of dim 2.
// Householder(2x2) collapses to planar rotation: x=X[1,0]; c=(x^2-1)/(1+x^2), s=2x/(1+x^2).
// enc feeds only enc_w1 => se_out GEMM eliminated via F_k = se_out_w @ enc_w1[k].

typedef __attribute__((ext_vector_type(8))) short short8;
typedef __attribute__((ext_vector_type(4))) float f32x4;

__device__ __forceinline__ float gelu_exact(float x) {
  return 0.5f * x * (1.0f + erff(x * 0.7071067811865475f));
}
__device__ __forceinline__ unsigned short f2bf(float f) {
  __hip_bfloat16 b = __float2bfloat16(f);
  return *reinterpret_cast<unsigned short*>(&b);
}
__device__ __forceinline__ float bf2f(unsigned short u) {
  return __uint_as_float((unsigned)u << 16);
}
__device__ __forceinline__ float bflo(unsigned u) { return __uint_as_float(u << 16); }
__device__ __forceinline__ float bfhi(unsigned u) { return __uint_as_float(u & 0xffff0000u); }
__device__ __forceinline__ unsigned packbf(float f0, float f1) {
  return (unsigned)f2bf(f0) | ((unsigned)f2bf(f1) << 16);
}
__device__ __forceinline__ void gload16(const void* g, void* l) {
  __builtin_amdgcn_global_load_lds((const __attribute__((address_space(1))) void*)g,
                                   (__attribute__((address_space(3))) void*)l, 16, 0, 0);
}
#define SCHEDB() __builtin_amdgcn_sched_barrier(0)

// ---------------- CSR build ----------------
__global__ void k_hist(const int* __restrict__ dst, int* __restrict__ deg, int E) {
  int i = blockIdx.x * 256 + threadIdx.x;
  if (i < E) atomicAdd(&deg[dst[i]], 1);
}

__global__ __launch_bounds__(1024)
void k_scan(const int* __restrict__ deg, int* __restrict__ rp, int* __restrict__ cur, int Nn) {
  __shared__ int part[1024];
  int t = threadIdx.x;
  int chunk = (Nn + 1023) >> 10;
  int s0 = t * chunk;
  int e0 = s0 + chunk; if (e0 > Nn) e0 = Nn;
  int s = 0;
  for (int i = s0; i < e0; ++i) s += deg[i];
  part[t] = s;
  __syncthreads();
  for (int off = 1; off < 1024; off <<= 1) {
    int v = (t >= off) ? part[t - off] : 0;
    __syncthreads();
    part[t] += v;
    __syncthreads();
  }
  int base = (t == 0) ? 0 : part[t - 1];
  for (int i = s0; i < e0; ++i) {
    rp[i] = base; cur[i] = base; base += deg[i];
  }
  if (t == 0) rp[Nn] = part[1023];
}

__global__ void k_fill(const int* __restrict__ src, const int* __restrict__ dst,
                       int* __restrict__ cur, int* __restrict__ srcs, int E) {
  int i = blockIdx.x * 256 + threadIdx.x;
  if (i < E) {
    int p = atomicAdd(&cur[dst[i]], 1);
    srcs[p] = src[i];
  }
}

// ---------------- LDS-tiled weight transpose fp32 [K,Nc] -> bf16 [Nc,K] ----------------
// 64x64 tile; coalesced global read AND coalesced write (old version had stride-2KB reads,
// 16x read amplification). Padded LDS kills bank conflicts on the transposed read.
__global__ __launch_bounds__(256)
void k_wT2(const float* __restrict__ W, unsigned short* __restrict__ Wt, int K, int Nc) {
  __shared__ float t[64][65];
  const float* Ws = W + (size_t)blockIdx.z * K * Nc;
  unsigned short* Wd = Wt + (size_t)blockIdx.z * K * Nc;
  int k0 = blockIdx.x * 64, n0 = blockIdx.y * 64;
#pragma unroll
  for (int p = 0; p < 16; ++p) {
    int idx = p * 256 + threadIdx.x;
    int nn = idx & 63, kk = idx >> 6;
    t[kk][nn] = Ws[(size_t)(k0 + kk) * Nc + n0 + nn];
  }
  __syncthreads();
#pragma unroll
  for (int p = 0; p < 16; ++p) {
    int idx = p * 256 + threadIdx.x;
    int kk = idx & 63, nn = idx >> 6;
    Wd[(size_t)(n0 + nn) * K + k0 + kk] = f2bf(t[kk][nn]);
  }
}

__global__ void k_cast(const float* __restrict__ src, unsigned short* __restrict__ dst, int n) {
  int i = blockIdx.x * 256 + threadIdx.x;
  if (i < n) dst[i] = f2bf(src[i]);
}

// fused bias: bf[k][n] = sum_e b_so[e]*enc_w1[k][e][n] + b_e1[k][n]
__global__ void k_bfuse(const float* __restrict__ b_so, const float* __restrict__ W_e1,
                        const float* __restrict__ b_e1, float* __restrict__ bf) {
  int k = blockIdx.y;
  int n = blockIdx.x * 256 + threadIdx.x;
  if (n >= 512) return;
  const float* W = W_e1 + (size_t)k * 512 * 512;
  float s = b_e1[(size_t)k * 512 + n];
  for (int e = 0; e < 512; ++e) s += b_so[e] * W[(size_t)e * 512 + n];
  bf[(size_t)k * 512 + n] = s;
}

// ---------------- bf16 MFMA GEMM: 128x128 tile, BK=64, 4 waves, double-buffered ----------------
// C = [R +] act(A @ W + bias), A bf16 row-major (dual-source concat along K),
// Wt = W^T bf16 [Nc, Ktot] row-major. fp32 accumulate. 64 KiB LDS -> 2 blocks/CU.
// Depth-2 counted-vmcnt schedule (proven round 9); XCD co-location via padded 1D grid.
// blockIdx.y batches independent GEMMs via sA/sC element strides (A1 and Cbf only).
// RES: 0=none, 1=fp32 residual, 2=bf16 residual. OP: emit rotation params from nr output.
template<int ACT, int RES, bool DUAL, bool W32, bool WBF, bool OP>
__global__ __launch_bounds__(256)
void k_mfma(const unsigned short* __restrict__ A1, const unsigned short* __restrict__ A2,
            int K1, int K2,
            const unsigned short* __restrict__ Wt, const float* __restrict__ bias,
            const float* R32, const unsigned short* Rbf,
            float* C32, unsigned short* Cbf, float* Op, int M, int Nc,
            size_t sA, size_t sC) {
  A1 += (size_t)blockIdx.y * sA;
  Cbf += (size_t)blockIdx.y * sC;
  const int mb_cnt = (M + 127) >> 7;
  const int nb_cnt = Nc >> 7;
  int u = blockIdx.x;
  int xcd = u & 7;
  int rest = u >> 3;
  int nb = rest % nb_cnt;
  int mb = (rest / nb_cnt) * 8 + xcd;
  if (mb >= mb_cnt) return;
  const int m0 = mb << 7, n0 = nb << 7;

  __shared__ unsigned short As[2][128 * 64];   // [buf][row][64] bf16, 128B rows, swizzled segs
  __shared__ unsigned short Bs[2][128 * 64];
  const int tid = threadIdx.x;
  const int lane = tid & 63, wv = tid >> 6;
  const int wr = (wv >> 1) * 64, wc = (wv & 1) * 64;  // wave's 64x64 subtile
  const int rA = lane & 15, kg = lane >> 4;
  const int Ktot = K1 + K2;
  const int nt = Ktot >> 6;

  f32x4 acc[4][4];
#pragma unroll
  for (int m = 0; m < 4; ++m)
#pragma unroll
    for (int n = 0; n < 4; ++n)
#pragma unroll
      for (int r = 0; r < 4; ++r) acc[m][n][r] = 0.f;

  // stage K-tile t into buffer b: 1024 16B-chunks per matrix, 4 issues x 256 thr.
  // linear LDS dest; swizzle applied on the GLOBAL source k-segment (involution).
  auto stage = [&](int t, int b) {
    int k0 = t << 6;
    const unsigned short* Asrc; int kc, lda;
    if (!DUAL || k0 < K1) { Asrc = A1; kc = k0; lda = K1; }
    else                  { Asrc = A2; kc = k0 - K1; lda = K2; }
#pragma unroll
    for (int is = 0; is < 4; ++is) {
      int chunk = is * 256 + tid;
      int row = chunk >> 3, seg = chunk & 7;
      int ks = seg ^ (row & 7);
      int gm = m0 + row; gm = gm < M ? gm : M - 1;
      gload16(Asrc + (size_t)gm * lda + kc + ks * 8, (char*)As[b] + (size_t)chunk * 16);
      gload16(Wt + (size_t)(n0 + row) * Ktot + k0 + ks * 8, (char*)Bs[b] + (size_t)chunk * 16);
    }
  };

  stage(0, 0);
  if (nt > 1) stage(1, 1);

  for (int t = 0; t < nt; ++t) {
    const int b = t & 1;
    // tile t's own loads complete; tile t+1's 8 loads may stay in flight
    if (t + 1 < nt) asm volatile("s_waitcnt vmcnt(8)" ::: "memory");
    else            asm volatile("s_waitcnt vmcnt(0)" ::: "memory");
    SCHEDB();
    __builtin_amdgcn_s_barrier();
    SCHEDB();

    short8 af[2][4], bq[2][4];
#pragma unroll
    for (int kk = 0; kk < 2; ++kk) {
#pragma unroll
      for (int m = 0; m < 4; ++m) {
        int row = wr + m * 16 + rA;
        int ks = (kk * 4 + kg) ^ (row & 7);
        af[kk][m] = *reinterpret_cast<const short8*>((const char*)As[b] + row * 128 + ks * 16);
      }
#pragma unroll
      for (int n = 0; n < 4; ++n) {
        int col = wc + n * 16 + rA;
        int ks = (kk * 4 + kg) ^ (col & 7);
        bq[kk][n] = *reinterpret_cast<const short8*>((const char*)Bs[b] + col * 128 + ks * 16);
      }
    }
    asm volatile("s_waitcnt lgkmcnt(0)" ::: "memory");
    SCHEDB();
    __builtin_amdgcn_s_barrier();   // all waves done reading buf b
    SCHEDB();
    if (t + 2 < nt) stage(t + 2, b);  // DMA into freed buffer, overlaps MFMA

    __builtin_amdgcn_s_setprio(1);
#pragma unroll
    for (int kk = 0; kk < 2; ++kk)
#pragma unroll
      for (int m = 0; m < 4; ++m)
#pragma unroll
        for (int n = 0; n < 4; ++n)
          acc[m][n] = __builtin_amdgcn_mfma_f32_16x16x32_bf16(af[kk][m], bq[kk][n],
                                                              acc[m][n], 0, 0, 0);
    __builtin_amdgcn_s_setprio(0);
  }

  // epilogue: C/D layout col=lane&15, row=(lane>>4)*4+reg  [m89]
#pragma unroll
  for (int m = 0; m < 4; ++m) {
    int gr0 = m0 + wr + m * 16 + kg * 4;
#pragma unroll
    for (int n = 0; n < 4; ++n) {
      int gc = n0 + wc + n * 16 + rA;
      float bv = bias[gc];
#pragma unroll
      for (int r = 0; r < 4; ++r) {
        int gr = gr0 + r;
        if (gr < M) {
          float v = acc[m][n][r] + bv;
          if (ACT == 1) v = gelu_exact(v);
          if (RES == 1) v += R32[(size_t)gr * Nc + gc];
          if (RES == 2) v += bf2f(Rbf[(size_t)gr * Nc + gc]);
          if (W32) C32[(size_t)gr * Nc + gc] = v;
          if (WBF) Cbf[(size_t)gr * Nc + gc] = f2bf(v);
          if (OP) {
            // nr column 4b+2 -> rotation (c,s) for bundle b = gc>>2
            if ((rA & 3) == 2) {
              float iv = 1.0f / (1.0f + v * v);
              float* op = Op + (size_t)gr * 256 + ((gc >> 2) << 1);
              op[0] = (v * v - 1.0f) * iv;
              op[1] = 2.0f * v * iv;
            }
          }
        }
      }
    }
  }
}

// ---------------- mean aggregation, edge-unrolled 8/4/1 for memory-level parallelism ----------------
template<int W, bool ROT>
__global__ __launch_bounds__(256)
void k_agg(const unsigned short* __restrict__ X, const int* __restrict__ rp,
           const int* __restrict__ srcs, const float* __restrict__ o,
           unsigned short* __restrict__ out, int Nn) {
  int wid = (blockIdx.x * 256 + threadIdx.x) >> 6;
  int lane = threadIdx.x & 63;
  if (wid >= Nn) return;
  constexpr int PE = W / 64;    // bf16 elems per lane: 8 (W=512) or 4 (W=256)
  float a[PE];
#pragma unroll
  for (int p = 0; p < PE; ++p) a[p] = 0.f;
  int beg = rp[wid], end = rp[wid + 1];
  int e = beg;
  if (PE == 8) {
    for (; e + 8 <= end; e += 8) {
      uint4 v[8];
#pragma unroll
      for (int q = 0; q < 8; ++q) {
        int s = srcs[e + q];
        v[q] = *reinterpret_cast<const uint4*>(X + (size_t)s * W + lane * 8);
      }
#pragma unroll
      for (int q = 0; q < 8; ++q) {
        a[0] += bflo(v[q].x); a[1] += bfhi(v[q].x); a[2] += bflo(v[q].y); a[3] += bfhi(v[q].y);
        a[4] += bflo(v[q].z); a[5] += bfhi(v[q].z); a[6] += bflo(v[q].w); a[7] += bfhi(v[q].w);
      }
    }
    for (; e + 4 <= end; e += 4) {
      uint4 v[4];
#pragma unroll
      for (int q = 0; q < 4; ++q) {
        int s = srcs[e + q];
        v[q] = *reinterpret_cast<const uint4*>(X + (size_t)s * W + lane * 8);
      }
#pragma unroll
      for (int q = 0; q < 4; ++q) {
        a[0] += bflo(v[q].x); a[1] += bfhi(v[q].x); a[2] += bflo(v[q].y); a[3] += bfhi(v[q].y);
        a[4] += bflo(v[q].z); a[5] += bfhi(v[q].z); a[6] += bflo(v[q].w); a[7] += bfhi(v[q].w);
      }
    }
    for (; e < end; ++e) {
      int s = srcs[e];
      uint4 v = *reinterpret_cast<const uint4*>(X + (size_t)s * W + lane * 8);
      a[0] += bflo(v.x); a[1] += bfhi(v.x); a[2] += bflo(v.y); a[3] += bfhi(v.y);
      a[4] += bflo(v.z); a[5] += bfhi(v.z); a[6] += bflo(v.w); a[7] += bfhi(v.w);
    }
  } else {
    for (; e + 4 <= end; e += 4) {
      uint2 v[4];
#pragma unroll
      for (int q = 0; q < 4; ++q) {
        int s = srcs[e + q];
        v[q] = *reinterpret_cast<const uint2*>(X + (size_t)s * W + lane * 4);
      }
#pragma unroll
      for (int q = 0; q < 4; ++q) {
        a[0] += bflo(v[q].x); a[1] += bfhi(v[q].x); a[2] += bflo(v[q].y); a[3] += bfhi(v[q].y);
      }
    }
    for (; e < end; ++e) {
      int s = srcs[e];
      uint2 v = *reinterpret_cast<const uint2*>(X + (size_t)s * W + lane * 4);
      a[0] += bflo(v.x); a[1] += bfhi(v.x); a[2] += bflo(v.y); a[3] += bfhi(v.y);
    }
  }
  float inv = (end > beg) ? 1.0f / (float)(end - beg) : 0.0f;
#pragma unroll
  for (int p = 0; p < PE; ++p) a[p] *= inv;
  if (ROT) {
    float4 oc = *reinterpret_cast<const float4*>(o + (size_t)wid * 256 + lane * 4); // c0,s0,c1,s1
    float m0 = oc.x * a[0] - oc.y * a[1];
    float m1 = oc.y * a[0] + oc.x * a[1];
    float m2 = oc.z * a[2] - oc.w * a[3];
    float m3 = oc.w * a[2] + oc.z * a[3];
    a[0] = m0; a[1] = m1; a[2] = m2; a[3] = m3;
  }
  unsigned short* op = out + (size_t)wid * W + lane * PE;
  if (PE == 8) {
    uint4 rv;
    rv.x = packbf(a[0], a[1]); rv.y = packbf(a[2], a[3]);
    rv.z = packbf(a[4], a[5]); rv.w = packbf(a[6], a[7]);
    *reinterpret_cast<uint4*>(op) = rv;
  } else {
    uint2 rv;
    rv.x = packbf(a[0], a[1]); rv.y = packbf(a[2], a[3]);
    *reinterpret_cast<uint2*>(op) = rv;
  }
}

// ---------------- LayerNorm + rotate-into-frame; bf16 outputs ----------------
__global__ __launch_bounds__(256)
void k_ln_rot(const float* __restrict__ h, const float* __restrict__ o,
              const float* __restrict__ g, const float* __restrict__ b,
              unsigned short* __restrict__ hn, unsigned short* __restrict__ y, int Nn) {
  int wid = (blockIdx.x * 256 + threadIdx.x) >> 6;
  int lane = threadIdx.x & 63;
  if (wid >= Nn) return;
  float4 v = reinterpret_cast<const float4*>(h + (size_t)wid * 256)[lane];
  float s = v.x + v.y + v.z + v.w;
  float ss = v.x * v.x + v.y * v.y + v.z * v.z + v.w * v.w;
#pragma unroll
  for (int off = 1; off < 64; off <<= 1) { s += __shfl_xor(s, off); ss += __shfl_xor(ss, off); }
  float mean = s * (1.0f / 256.0f);
  float var = ss * (1.0f / 256.0f) - mean * mean;
  float rs = rsqrtf(var + 1e-5f);
  float4 gg = reinterpret_cast<const float4*>(g)[lane];
  float4 bb = reinterpret_cast<const float4*>(b)[lane];
  float h0 = (v.x - mean) * rs * gg.x + bb.x;
  float h1 = (v.y - mean) * rs * gg.y + bb.y;
  float h2 = (v.z - mean) * rs * gg.z + bb.z;
  float h3 = (v.w - mean) * rs * gg.w + bb.w;
  uint2 hv; hv.x = packbf(h0, h1); hv.y = packbf(h2, h3);
  *reinterpret_cast<uint2*>(hn + (size_t)wid * 256 + lane * 4) = hv;
  float4 oc = *reinterpret_cast<const float4*>(o + (size_t)wid * 256 + lane * 4); // c0,s0,c1,s1
  float y0 =  oc.x * h0 + oc.y * h1;
  float y1 = -oc.y * h0 + oc.x * h1;
  float y2 =  oc.z * h2 + oc.w * h3;
  float y3 = -oc.w * h2 + oc.z * h3;
  uint2 yv; yv.x = packbf(y0, y1); yv.y = packbf(y2, y3);
  *reinterpret_cast<uint2*>(y + (size_t)wid * 256 + lane * 4) = yv;
}

// ---------------- final: out = LN(h) @ w_out + b_out ----------------
__global__ __launch_bounds__(256)
void k_final(const float* __restrict__ h, const float* __restrict__ g,
             const float* __restrict__ b, const float* __restrict__ wout,
             const float* __restrict__ bout, float* __restrict__ out, int Nn) {
  int wid = (blockIdx.x * 256 + threadIdx.x) >> 6;
  int lane = threadIdx.x & 63;
  if (wid >= Nn) return;
  float4 v = reinterpret_cast<const float4*>(h + (size_t)wid * 256)[lane];
  float s = v.x + v.y + v.z + v.w;
  float ss = v.x * v.x + v.y * v.y + v.z * v.z + v.w * v.w;
#pragma unroll
  for (int off = 1; off < 64; off <<= 1) { s += __shfl_xor(s, off); ss += __shfl_xor(ss, off); }
  float mean = s * (1.0f / 256.0f);
  float var = ss * (1.0f / 256.0f) - mean * mean;
  float rs = rsqrtf(var + 1e-5f);
  float4 gg = reinterpret_cast<const float4*>(g)[lane];
  float4 bb = reinterpret_cast<const float4*>(b)[lane];
  float hv[4];
  hv[0] = (v.x - mean) * rs * gg.x + bb.x;
  hv[1] = (v.y - mean) * rs * gg.y + bb.y;
  hv[2] = (v.z - mean) * rs * gg.z + bb.z;
  hv[3] = (v.w - mean) * rs * gg.w + bb.w;
  int c0 = lane * 4;
  float dots[5];
#pragma unroll
  for (int j = 0; j < 5; ++j) {
    float p = hv[0] * wout[(size_t)(c0 + 0) * 5 + j] + hv[1] * wout[(size_t)(c0 + 1) * 5 + j]
            + hv[2] * wout[(size_t)(c0 + 2) * 5 + j] + hv[3] * wout[(size_t)(c0 + 3) * 5 + j];
#pragma unroll
    for (int off = 1; off < 64; off <<= 1) p += __shfl_xor(p, off);
    dots[j] = p;
  }
  if (lane == 0) {
#pragma unroll
    for (int j = 0; j < 5; ++j) out[(size_t)wid * 5 + j] = dots[j] + bout[j];
  }
}

// ---------------- host-side launch ----------------
extern "C" void kernel_launch(void* const* d_in, const int* in_sizes, int n_in,
                              void* d_out, int out_size, void* d_ws, size_t ws_size,
                              hipStream_t stream) {
  const float* x       = (const float*)d_in[0];
  const int*   ei      = (const int*)  d_in[1];
  const float* w_in    = (const float*)d_in[2];
  const float* b_in    = (const float*)d_in[3];
  const float* se_in_w = (const float*)d_in[4];
  const float* se_in_b = (const float*)d_in[5];
  const float* sage_w1 = (const float*)d_in[6];
  const float* sage_b1 = (const float*)d_in[7];
  const float* sage_w2 = (const float*)d_in[8];
  const float* sage_b2 = (const float*)d_in[9];
  const float* se_out_w= (const float*)d_in[10];
  const float* se_out_b= (const float*)d_in[11];
  const float* enc_w1  = (const float*)d_in[12];
  const float* enc_b1  = (const float*)d_in[13];
  const float* enc_w2  = (const float*)d_in[14];
  const float* enc_b2  = (const float*)d_in[15];
  const float* ln_g    = (const float*)d_in[16];
  const float* ln_b    = (const float*)d_in[17];
  const float* bdl_w1  = (const float*)d_in[18];
  const float* bdl_b1  = (const float*)d_in[19];
  const float* bdl_w2  = (const float*)d_in[20];
  const float* bdl_b2  = (const float*)d_in[21];
  const float* oln_g   = (const float*)d_in[22];
  const float* oln_b   = (const float*)d_in[23];
  const float* w_out   = (const float*)d_in[24];
  const float* b_out   = (const float*)d_in[25];
  float* out = (float*)d_out;

  const int HID = 256, SW = 512;
  const int N = in_sizes[0] / HID;   // 30000
  const int E = in_sizes[1] / 2;     // 480000

  // ---- workspace layout (~187 MB) ----
  float* ws = (float*)d_ws;
  float* h32 = ws;                              // [N,256] fp32 residual carrier
  float* o   = h32 + (size_t)N * HID;           // [N,256] rotation (c,s)*128
  unsigned short* h_bf = (unsigned short*)(o + (size_t)N * HID);  // [N,256]
  unsigned short* z_bf = h_bf + (size_t)N * HID;                  // [N,512]
  unsigned short* t_bf = z_bf + (size_t)N * SW;                   // [N,512]
  unsigned short* u_bf = t_bf + (size_t)N * SW;                   // [N,512]
  unsigned short* wts = u_bf + (size_t)N * SW;
  size_t off = 0;
  unsigned short* wt_in    = wts + off; off += 256 * 256;
  unsigned short* wt_se_in = wts + off; off += 512 * 256;
  unsigned short* wt_sage1 = wts + off; off += (size_t)5 * 512 * 1024;
  unsigned short* wt_sage2 = wts + off; off += (size_t)5 * 512 * 512;
  unsigned short* so_bf    = wts + off; off += 512 * 512;          // cast(se_out_w), native layout
  unsigned short* wt_enc1  = wts + off; off += (size_t)2 * 512 * 512;
  unsigned short* wt_enc2  = wts + off; off += (size_t)2 * 512 * 512;
  unsigned short* wt_bdl1  = wts + off; off += (size_t)2 * 256 * 512;
  unsigned short* wt_bdl2  = wts + off; off += (size_t)2 * 256 * 256;
  unsigned short* wt_f     = wts + off; off += (size_t)2 * 512 * 512; // fused se_out@enc1
  float* bf_f = (float*)(wts + off); off += 2 * 512 * 2;              // fused bias [2][512]
  float* zb   = (float*)(wts + off); off += 512 * 2;                  // zero bias
  int* deg  = (int*)(wts + off);
  int* rp   = deg + N;
  int* cur  = rp + N + 1;
  int* srcs = cur + N;
  size_t need = (size_t)((char*)(srcs + E) - (char*)d_ws);
  if (ws_size < need) return;

  // aliases (lifetime-disjoint)
  unsigned short* xbf = u_bf;
  unsigned short* hn  = z_bf;
  unsigned short* y   = z_bf + (size_t)N * HID;
  unsigned short* msg = t_bf;
  unsigned short* g2  = u_bf;

  const int* esrc = ei;
  const int* edst = ei + E;

  auto cdiv = [](int a, int b) { return (a + b - 1) / b; };
  dim3 blk(256);
  int mb_cnt = cdiv(N, 128);                    // 235
  int mgrp = cdiv(mb_cnt, 8);                   // 30
  int g_g256 = mgrp * 8 * 2;                    // Nc=256 -> 480 blocks (padded)
  int g_g512 = mgrp * 8 * 4;                    // Nc=512 -> 960 blocks (padded)
  int g_F    = 1 * 8 * 4;                       // M=512, Nc=512 -> 32 blocks (16 active)
  int gw = cdiv(N * 64, 256);

  // ---- CSR build ----
  hipMemsetAsync(deg, 0, sizeof(int) * N, stream);
  k_hist<<<cdiv(E, 256), blk, 0, stream>>>(edst, deg, E);
  k_scan<<<1, 1024, 0, stream>>>(deg, rp, cur, N);
  k_fill<<<cdiv(E, 256), blk, 0, stream>>>(esrc, edst, cur, srcs, E);

  // ---- weight prep (LDS-tiled transpose: coalesced both sides) ----
  auto wT = [&](const float* W, unsigned short* Wt, int K, int Nc, int cnt) {
    k_wT2<<<dim3(K / 64, Nc / 64, cnt), blk, 0, stream>>>(W, Wt, K, Nc);
  };
  wT(w_in, wt_in, 256, 256, 1);
  wT(se_in_w, wt_se_in, 256, 512, 1);
  wT(sage_w1, wt_sage1, 1024, 512, 5);
  wT(sage_w2, wt_sage2, 512, 512, 5);
  wT(enc_w1, wt_enc1, 512, 512, 2);
  wT(enc_w2, wt_enc2, 512, 512, 2);
  wT(bdl_w1, wt_bdl1, 512, 256, 2);
  wT(bdl_w2, wt_bdl2, 256, 256, 2);
  k_cast<<<cdiv(512 * 512, 256), blk, 0, stream>>>(se_out_w, so_bf, 512 * 512);
  k_cast<<<cdiv(N * HID, 256), blk, 0, stream>>>(x, xbf, N * HID);
  hipMemsetAsync(zb, 0, 512 * sizeof(float), stream);
  k_bfuse<<<dim3(2, 2), blk, 0, stream>>>(se_out_b, enc_w1, enc_b1, bf_f);
  // F_k = se_out_w @ enc_w1[k] -> wt_f[k] in W^T layout; both k batched via grid.y
  k_mfma<0, 0, false, false, true, false><<<dim3(g_F, 2), blk, 0, stream>>>(
      wt_enc1, nullptr, 512, 0, so_bf, zb,
      nullptr, nullptr, nullptr, wt_f, nullptr, 512, 512,
      (size_t)512 * 512, (size_t)512 * 512);

  // ---- h = gelu(x @ w_in + b_in) : fp32 + bf16 ----
  k_mfma<1, 0, false, true, true, false><<<g_g256, blk, 0, stream>>>(
      xbf, nullptr, 256, 0, wt_in, b_in, nullptr, nullptr, h32, h_bf, nullptr, N, 256, 0, 0);

  for (int k = 0; k < 2; ++k) {
    // z = gelu(h @ se_in_w + b)
    k_mfma<1, 0, false, false, true, false><<<g_g512, blk, 0, stream>>>(
        h_bf, nullptr, 256, 0, wt_se_in, se_in_b, nullptr, nullptr, nullptr, z_bf, nullptr,
        N, 512, 0, 0);
    for (int i = 0; i < 5; ++i) {
      k_agg<512, false><<<gw, blk, 0, stream>>>(z_bf, rp, srcs, nullptr, t_bf, N);
      k_mfma<1, 0, true, false, true, false><<<g_g512, blk, 0, stream>>>(
          z_bf, t_bf, 512, 512, wt_sage1 + (size_t)i * 512 * 1024,
          sage_b1 + (size_t)i * SW, nullptr, nullptr, nullptr, u_bf, nullptr, N, 512, 0, 0);
      k_mfma<0, 2, false, false, true, false><<<g_g512, blk, 0, stream>>>(
          u_bf, nullptr, 512, 0, wt_sage2 + (size_t)i * 512 * 512,
          sage_b2 + (size_t)i * SW, nullptr, z_bf, nullptr, z_bf, nullptr, N, 512, 0, 0);
    }
    // u = gelu(z @ F_k + bf_k)   (se_out folded into enc1)
    k_mfma<1, 0, false, false, true, false><<<g_g512, blk, 0, stream>>>(
        z_bf, nullptr, 512, 0, wt_f + (size_t)k * 512 * 512,
        bf_f + (size_t)k * 512, nullptr, nullptr, nullptr, u_bf, nullptr, N, 512, 0, 0);
    // nr = u @ enc_w2 + b ; rotation params fused into epilogue (only o written)
    k_mfma<0, 0, false, false, false, true><<<g_g512, blk, 0, stream>>>(
        u_bf, nullptr, 512, 0, wt_enc2 + (size_t)k * 512 * 512,
        enc_b2 + (size_t)k * SW, nullptr, nullptr, nullptr, nullptr, o, N, 512, 0, 0);
    // hn=LN(h), y=O@hn; msg=O^T@mean(y)
    k_ln_rot<<<gw, blk, 0, stream>>>(h32, o, ln_g + (size_t)k * HID, ln_b + (size_t)k * HID, hn, y, N);
    k_agg<256, true><<<gw, blk, 0, stream>>>(y, rp, srcs, o, msg, N);
    // h = h + gelu([hn|msg] @ bdl_w1 + b1) @ bdl_w2 + b2
    k_mfma<1, 0, true, false, true, false><<<g_g256, blk, 0, stream>>>(
        hn, msg, 256, 256, wt_bdl1 + (size_t)k * 256 * 512,
        bdl_b1 + (size_t)k * HID, nullptr, nullptr, nullptr, g2, nullptr, N, 256, 0, 0);
    k_mfma<0, 1, false, true, true, false><<<g_g256, blk, 0, stream>>>(
        g2, nullptr, 256, 0, wt_bdl2 + (size_t)k * 256 * 256,
        bdl_b2 + (size_t)k * HID, h32, nullptr, h32, h_bf, nullptr, N, 256, 0, 0);
  }

  k_final<<<gw, blk, 0, stream>>>(h32, oln_g, oln_b, w_out, b_out, out, N);
}